// Round 2
// baseline (335.907 us; speedup 1.0000x reference)
//
#include <hip/hip_runtime.h>
#include <hip/hip_bf16.h>

typedef short  short8  __attribute__((ext_vector_type(8)));
typedef float  f32x16  __attribute__((ext_vector_type(16)));
typedef unsigned short ushort_t;

#define B_    8
#define CIN_  64
#define COUT_ 64
#define MID_  64
#define HH    256
#define WW    256
#define NP_   4
#define NL_   5

#define TR 8               // output rows per block strip
#define TC 32              // output cols per tile
#define NJT 8              // 8*32 = 256
#define SR 10              // slab rows (TR + 2 halo)
#define SCC 36             // slab cols (TC + 2 halo + 2 align pad; cols 0 and 35 never read)
#define SLAB_U32 (SR*8*SCC*4)    // 11520 u32 = 46080 B
#define W_SHORTS (9*8*COUT_*8)   // 36864 shorts = 73728 B
#define NUNITS (SR*8*4*18)       // 5760 load units (each unit = 2 cols x 2 planes)
#define NU 12                    // ceil(5760/512)
#define LASTU (NUNITS - 512*(NU-1))  // 128 active threads in last unit-iter

// ---------------- Kernel 1: hypernet -> combined bf16 weights ----------------
// wsW layout: [b][khkw][ci>>3][co][ci&7] shorts (unchanged, verified)
__global__ __launch_bounds__(256)
void build_weights(const float* __restrict__ h, const float* __restrict__ index,
                   const float* __restrict__ conv_weight,
                   const float* __restrict__ W_wp, const float* __restrict__ b_wp,
                   const float* __restrict__ W_wi, const float* __restrict__ b_wi,
                   const float* __restrict__ W_we, const float* __restrict__ b_we,
                   ushort_t* __restrict__ wsW) {
    const int bb  = blockIdx.x / 9;
    const int ch  = blockIdx.x - bb * 9;
    const int tid = threadIdx.x;

    __shared__ float pre_s[64 * 66];
    __shared__ float chunk_s[64 * 64];

    float hv[NP_], iv[NL_];
#pragma unroll
    for (int p = 0; p < NP_; ++p) hv[p] = h[bb * NP_ + p];
#pragma unroll
    for (int l = 0; l < NL_; ++l) iv[l] = index[l];

#pragma unroll
    for (int k = 0; k < 16; ++k) {
        const int m = tid + k * 256;
        float a = b_wp[m] + b_wi[m];
#pragma unroll
        for (int p = 0; p < NP_; ++p) a += hv[p] * W_wp[m * NP_ + p];
#pragma unroll
        for (int l = 0; l < NL_; ++l) a += iv[l] * W_wi[m * NL_ + l];
        pre_s[(m >> 6) * 66 + (m & 63)] = a;
    }
#pragma unroll
    for (int k = 0; k < 16; ++k) {
        const int f = tid + k * 256;
        chunk_s[f] = W_we[ch * 4096 + f];
    }
    __syncthreads();

    const int ci = tid & 63;
    const int g  = tid >> 6;
    float acc[16];
#pragma unroll
    for (int u = 0; u < 16; ++u) acc[u] = 0.f;

#pragma unroll
    for (int mid = 0; mid < 64; mid += 2) {
        const float2 pv = *(const float2*)&pre_s[ci * 66 + mid];
#pragma unroll
        for (int u = 0; u < 16; ++u) {
            const float2 wv = *(const float2*)&chunk_s[(g + 4 * u) * 64 + mid];
            acc[u] += pv.x * wv.x + pv.y * wv.y;
        }
    }

#pragma unroll
    for (int u = 0; u < 16; ++u) {
        const int o9 = ch * 64 + g + 4 * u;
        const int co = o9 / 9;
        const int r  = o9 - co * 9;
        const float val = acc[u] + b_we[o9] + conv_weight[(co * CIN_ + ci) * 9 + r];
        __hip_bfloat16 hb = __float2bfloat16(val);
        ushort_t bits; __builtin_memcpy(&bits, &hb, 2);
        wsW[(((bb * 9 + r) * 8 + (ci >> 3)) * COUT_ + co) * 8 + (ci & 7)] = bits;
    }
}

// ---------------- Kernel 2: MFMA implicit-GEMM conv ----------------
// Slab (u32, each = bf16 ci-pair): [r 10][g 8][c 36][p 4]; slab col c <-> gc = j0-2+c.
// Unit k = (r,g,p,cp): loads x[ci..ci+1][gr][gc0..gc0+1] as two float2 (even gc0 -> 8B aligned).
// RAW loads into regs; convert+mask at consume time (next iter) so loads stay in flight.

__device__ __forceinline__ void load_fast(const float* __restrict__ xb,
                                          const int (&rel)[NU], int j0,
                                          float2 (&va)[NU], float2 (&vb)[NU]) {
#pragma unroll
    for (int k = 0; k < NU; ++k) {
        const float* p0 = xb + (rel[k] + j0);
        va[k] = *(const float2*)p0;
        vb[k] = *(const float2*)(p0 + HH * WW);
    }
}

__device__ __forceinline__ void load_edge(const float* __restrict__ xb,
                                          const int (&rel)[NU], const int (&cc2)[NU], int j0,
                                          float2 (&va)[NU], float2 (&vb)[NU]) {
#pragma unroll
    for (int k = 0; k < NU; ++k) {
        const int base = rel[k] - cc2[k];          // ci*HW + grc*W
        const int gc0  = j0 + cc2[k];
        const int c0 = gc0 < 0 ? 0 : (gc0 > WW - 1 ? WW - 1 : gc0);
        const int g1 = gc0 + 1;
        const int c1 = g1 < 0 ? 0 : (g1 > WW - 1 ? WW - 1 : g1);
        va[k].x = xb[base + c0];
        va[k].y = xb[base + c1];
        vb[k].x = xb[base + HH * WW + c0];
        vb[k].y = xb[base + HH * WW + c1];
    }
}

__global__ __launch_bounds__(512, 2)
void hyperconv(const float* __restrict__ x, const ushort_t* __restrict__ wsW,
               const float* __restrict__ conv_bias,
               const float* __restrict__ h, const float* __restrict__ index,
               const float* __restrict__ W_bp, const float* __restrict__ b_bp,
               const float* __restrict__ W_bi, const float* __restrict__ b_bi,
               float* __restrict__ out) {
    __shared__ __align__(16) ushort_t Wl[W_SHORTS];   // 73728 B
    __shared__ __align__(16) unsigned Slab[SLAB_U32]; // 46080 B
    __shared__ float biasl[COUT_];

    const int tid   = threadIdx.x;
    const int bb    = blockIdx.x >> 5;
    const int strip = blockIdx.x & 31;
    const int i0    = strip * TR;
    const float* xb = x + bb * CIN_ * HH * WW;

    // ---- per-unit descriptors (registers; fully static indexing) ----
    int rel[NU], cc2[NU], sidx[NU];
    unsigned rmask = 0u;
#pragma unroll
    for (int k = 0; k < NU; ++k) {
        int u = tid + k * 512;
        const bool uok = (u < NUNITS);
        if (!uok) u = NUNITS - 1;
        const int cp = u % 18;
        const int t  = u / 18;          // (r*8+g)*4+p
        const int p  = t & 3;
        const int rg = t >> 2;          // r*8+g
        const int g  = rg & 7;
        const int r  = rg >> 3;
        const int gr = i0 - 1 + r;
        const int grc = gr < 0 ? 0 : (gr > HH - 1 ? HH - 1 : gr);
        const int ci = g * 8 + 2 * p;
        cc2[k]  = 2 * cp - 2;                        // gc0 = j0 + cc2
        rel[k]  = ci * (HH * WW) + grc * WW + cc2[k];
        sidx[k] = (rg * SCC + 2 * cp) * 4 + p;
        if (uok && (unsigned)gr < (unsigned)HH) rmask |= 1u << k;
    }

    // ---- stage weights (plain reg->LDS so lgkmcnt covers visibility) ----
    {
        const uint4* src = (const uint4*)(wsW + bb * W_SHORTS);
        uint4* dst = (uint4*)Wl;
#pragma unroll
        for (int i = 0; i < (W_SHORTS / 8) / 512; ++i)   // 9 exact
            dst[tid + i * 512] = src[tid + i * 512];
    }
    // ---- per-sample bias ----
    if (tid < COUT_) {
        const int co = tid;
        float a = conv_bias[co] + b_bp[co] + b_bi[co];
#pragma unroll
        for (int p = 0; p < NP_; ++p) a += h[bb * NP_ + p] * W_bp[co * NP_ + p];
#pragma unroll
        for (int l = 0; l < NL_; ++l) a += index[l] * W_bi[co * NL_ + l];
        biasl[co] = a;
    }

    // ---- prefetch tile 0 (raw, stays in flight) ----
    float2 va[NU], vb[NU];
    load_edge(xb, rel, cc2, 0, va, vb);

    const int lane = tid & 63;
    const int wv   = tid >> 6;     // output row within strip
    const int n    = lane & 31;    // output col within tile / co for A
    const int hl   = lane >> 5;    // k-half

    for (int jt = 0; jt < NJT; ++jt) {
        const int j0 = jt * TC;
        // all waves done READING slab (prev iter); does NOT drain vmcnt
        __builtin_amdgcn_sched_barrier(0);
        __builtin_amdgcn_s_barrier();
        __builtin_amdgcn_sched_barrier(0);

        // convert current tile regs -> slab (vmcnt waits happen here, loads had a
        // full compute phase to drain)
#pragma unroll
        for (int k = 0; k < NU; ++k) {
            if (k == NU - 1 && tid >= LASTU) continue;
            const bool rok = (rmask >> k) & 1u;
            const int gc0 = j0 + cc2[k];
            const bool ok0 = rok && ((unsigned)gc0 < (unsigned)WW);
            const bool ok1 = rok && ((unsigned)(gc0 + 1) < (unsigned)WW);
            const float ax = ok0 ? va[k].x : 0.f;
            const float bx = ok0 ? vb[k].x : 0.f;
            const float ay = ok1 ? va[k].y : 0.f;
            const float by = ok1 ? vb[k].y : 0.f;
            const __hip_bfloat162 lo2 = __float22bfloat162_rn(make_float2(ax, bx));
            const __hip_bfloat162 hi2 = __float22bfloat162_rn(make_float2(ay, by));
            unsigned ulo, uhi;
            __builtin_memcpy(&ulo, &lo2, 4);
            __builtin_memcpy(&uhi, &hi2, 4);
            Slab[sidx[k]]     = ulo;
            Slab[sidx[k] + 4] = uhi;
        }

        // issue next tile's raw loads (no consumption -> no waits emitted)
        if (jt + 1 < NJT) {
            if (jt + 1 == NJT - 1) load_edge(xb, rel, cc2, (jt + 1) * TC, va, vb);
            else                   load_fast(xb, rel, (jt + 1) * TC, va, vb);
        }

        // own LDS writes committed, then barrier: slab visible to all waves.
        // vmcnt NOT drained (prefetch stays in flight).
        __builtin_amdgcn_sched_barrier(0);
        asm volatile("s_waitcnt lgkmcnt(0)" ::: "memory");
        __builtin_amdgcn_sched_barrier(0);
        __builtin_amdgcn_s_barrier();
        __builtin_amdgcn_sched_barrier(0);

        f32x16 a0 = {}, a1 = {};
        const ushort_t* sl = (const ushort_t*)Slab;
#pragma unroll
        for (int kh = 0; kh < 3; ++kh)
#pragma unroll
            for (int kw = 0; kw < 3; ++kw) {
                const int khkw = kh * 3 + kw;
#pragma unroll
                for (int kk = 0; kk < 4; ++kk) {
                    const int gA = khkw * 8 + 2 * kk + hl;
                    const short8 A0 = *(const short8*)&Wl[(gA * 64 + n) * 8];
                    const short8 A1 = *(const short8*)&Wl[(gA * 64 + n + 32) * 8];
                    const int gB = ((wv + kh) * 8 + 2 * kk + hl) * SCC + (n + kw + 1);
                    const short8 Bf = *(const short8*)&sl[gB * 8];
                    a0 = __builtin_amdgcn_mfma_f32_32x32x16_bf16(A0, Bf, a0, 0, 0, 0);
                    a1 = __builtin_amdgcn_mfma_f32_32x32x16_bf16(A1, Bf, a1, 0, 0, 0);
                }
            }

        // epilogue: line-aligned stores
        float* op = out + (size_t)(bb * COUT_) * (HH * WW) + (i0 + wv) * WW + j0 + n;
#pragma unroll
        for (int r = 0; r < 16; ++r) {
            const int co = (r & 3) + 8 * (r >> 2) + 4 * hl;
            op[co * (HH * WW)] = a0[r] + biasl[co];
        }
#pragma unroll
        for (int r = 0; r < 16; ++r) {
            const int co = (r & 3) + 8 * (r >> 2) + 4 * hl + 32;
            op[co * (HH * WW)] = a1[r] + biasl[co];
        }
    }
}

extern "C" void kernel_launch(void* const* d_in, const int* in_sizes, int n_in,
                              void* d_out, int out_size, void* d_ws, size_t ws_size,
                              hipStream_t stream) {
    const float* x           = (const float*)d_in[0];
    const float* h           = (const float*)d_in[1];
    const float* index       = (const float*)d_in[2];
    const float* conv_weight = (const float*)d_in[3];
    const float* conv_bias   = (const float*)d_in[4];
    const float* W_wp        = (const float*)d_in[5];
    const float* b_wp        = (const float*)d_in[6];
    const float* W_wi        = (const float*)d_in[7];
    const float* b_wi        = (const float*)d_in[8];
    const float* W_we        = (const float*)d_in[9];
    const float* b_we        = (const float*)d_in[10];
    const float* W_bp        = (const float*)d_in[11];
    const float* b_bp        = (const float*)d_in[12];
    const float* W_bi        = (const float*)d_in[13];
    const float* b_bi        = (const float*)d_in[14];

    float* out = (float*)d_out;
    ushort_t* wsW = (ushort_t*)d_ws;   // 8 * 36864 * 2 = 589824 B

    build_weights<<<72, 256, 0, stream>>>(
        h, index, conv_weight, W_wp, b_wp, W_wi, b_wi, W_we, b_we, wsW);

    hyperconv<<<256, 512, 0, stream>>>(
        x, wsW, conv_bias, h, index, W_bp, b_bp, W_bi, b_bi, out);
}